// Round 1
// baseline (1218.903 us; speedup 1.0000x reference)
//
#include <hip/hip_runtime.h>

#define N_NODES 50000
#define N_EDGES 800000
#define DIN 256
#define DH 128
#define NL 1000

// ---------------- CSR build ----------------

__global__ void count_deg_kernel(const int* __restrict__ dst, int* __restrict__ deg) {
    int e = blockIdx.x * blockDim.x + threadIdx.x;
    if (e < N_EDGES) atomicAdd(&deg[dst[e]], 1);
}

// In-place exclusive scan of deg[0..N-1] -> offsets, writes off[N]=E. One block.
__global__ __launch_bounds__(1024) void scan_kernel(int* __restrict__ off) {
    __shared__ int lds[1024];
    const int t = threadIdx.x;
    const int CH = (N_NODES + 1023) / 1024;  // 49
    const int lo = t * CH;
    const int hi = (lo + CH < N_NODES) ? (lo + CH) : N_NODES;
    int s = 0;
    for (int i = lo; i < hi; ++i) s += off[i];
    lds[t] = s;
    __syncthreads();
    for (int o = 1; o < 1024; o <<= 1) {
        int v = (t >= o) ? lds[t - o] : 0;
        __syncthreads();
        lds[t] += v;
        __syncthreads();
    }
    int run = (t == 0) ? 0 : lds[t - 1];
    for (int i = lo; i < hi; ++i) {
        int v = off[i];
        off[i] = run;
        run += v;
    }
    if (t == 1023) off[N_NODES] = lds[1023];
}

__global__ void scatter_eid_kernel(const int* __restrict__ dst, const int* __restrict__ off,
                                   int* __restrict__ cur, int* __restrict__ eid) {
    int e = blockIdx.x * blockDim.x + threadIdx.x;
    if (e < N_EDGES) {
        int d = dst[e];
        int p = off[d] + atomicAdd(&cur[d], 1);
        eid[p] = e;
    }
}

// ---------------- GEMMs (fp32 vector baseline) ----------------

// h = relu(x @ W_in + b_in)   [N,256]x[256,128] -> [N,128]
// block: 128 threads (thread = out column), 8 rows per block.
__global__ __launch_bounds__(128) void gemm_in_kernel(const float* __restrict__ x,
                                                      const float* __restrict__ W,
                                                      const float* __restrict__ b,
                                                      float* __restrict__ h) {
    const int d = threadIdx.x;
    const int row0 = blockIdx.x * 8;
    float acc[8] = {0.f, 0.f, 0.f, 0.f, 0.f, 0.f, 0.f, 0.f};
    for (int k = 0; k < DIN; k += 4) {
        float4 xv[8];
#pragma unroll
        for (int r = 0; r < 8; ++r)
            xv[r] = *reinterpret_cast<const float4*>(&x[(size_t)(row0 + r) * DIN + k]);
#pragma unroll
        for (int kk = 0; kk < 4; ++kk) {
            float w = W[(k + kk) * DH + d];
#pragma unroll
            for (int r = 0; r < 8; ++r)
                acc[r] += (&xv[r].x)[kk] * w;
        }
    }
    const float bias = b[d];
#pragma unroll
    for (int r = 0; r < 8; ++r)
        h[(size_t)(row0 + r) * DH + d] = fmaxf(acc[r] + bias, 0.f);
}

// Pull-aggregation: one block per node, thread = feature dim.
// agg[n] = sum_{e: dst=n} ppi_w[e]*h[src[e]] ; res likewise with self_w.
__global__ __launch_bounds__(128) void aggregate_kernel(const float* __restrict__ h,
                                                        const int* __restrict__ off,
                                                        const int* __restrict__ eid,
                                                        const int* __restrict__ src,
                                                        const float* __restrict__ self_w,
                                                        const float* __restrict__ ppi_w,
                                                        float* __restrict__ agg,
                                                        float* __restrict__ res) {
    const int node = blockIdx.x;
    const int d = threadIdx.x;
    const int lo = off[node], hi = off[node + 1];
    float aa = 0.f, rr = 0.f;
    for (int i = lo; i < hi; ++i) {
        int e = eid[i];
        int s = src[e];
        float wp = ppi_w[e];
        float ws = self_w[e];
        float v = h[(size_t)s * DH + d];
        aa += wp * v;
        rr += ws * v;
    }
    agg[(size_t)node * DH + d] = aa;
    res[(size_t)node * DH + d] = rr;
}

// h_new = relu(agg @ W + b) + res   [N,128]x[128,128]
__global__ __launch_bounds__(128) void gemm_update_kernel(const float* __restrict__ agg,
                                                          const float* __restrict__ res,
                                                          const float* __restrict__ W,
                                                          const float* __restrict__ b,
                                                          float* __restrict__ h) {
    const int d = threadIdx.x;
    const int row0 = blockIdx.x * 8;
    float acc[8] = {0.f, 0.f, 0.f, 0.f, 0.f, 0.f, 0.f, 0.f};
    for (int k = 0; k < DH; k += 4) {
        float4 av[8];
#pragma unroll
        for (int r = 0; r < 8; ++r)
            av[r] = *reinterpret_cast<const float4*>(&agg[(size_t)(row0 + r) * DH + k]);
#pragma unroll
        for (int kk = 0; kk < 4; ++kk) {
            float w = W[(k + kk) * DH + d];
#pragma unroll
            for (int r = 0; r < 8; ++r)
                acc[r] += (&av[r].x)[kk] * w;
        }
    }
    const float bias = b[d];
#pragma unroll
    for (int r = 0; r < 8; ++r) {
        size_t idx = (size_t)(row0 + r) * DH + d;
        h[idx] = fmaxf(acc[r] + bias, 0.f) + res[idx];
    }
}

// out = h @ W_out + b_out   [N,128]x[128,1000]
// grid: (4, N/8), block 256 (thread = out column), 8 rows per block.
__global__ __launch_bounds__(256) void gemm_out_kernel(const float* __restrict__ h,
                                                       const float* __restrict__ W,
                                                       const float* __restrict__ b,
                                                       float* __restrict__ out) {
    const int c = blockIdx.x * 256 + threadIdx.x;
    const int row0 = blockIdx.y * 8;
    if (c >= NL) return;
    float acc[8] = {0.f, 0.f, 0.f, 0.f, 0.f, 0.f, 0.f, 0.f};
    for (int k = 0; k < DH; k += 4) {
        float4 hv[8];
#pragma unroll
        for (int r = 0; r < 8; ++r)
            hv[r] = *reinterpret_cast<const float4*>(&h[(size_t)(row0 + r) * DH + k]);
#pragma unroll
        for (int kk = 0; kk < 4; ++kk) {
            float w = W[(size_t)(k + kk) * NL + c];
#pragma unroll
            for (int r = 0; r < 8; ++r)
                acc[r] += (&hv[r].x)[kk] * w;
        }
    }
    const float bias = b[c];
#pragma unroll
    for (int r = 0; r < 8; ++r)
        out[(size_t)(row0 + r) * NL + c] = acc[r] + bias;
}

// ---------------- launch ----------------

extern "C" void kernel_launch(void* const* d_in, const int* in_sizes, int n_in,
                              void* d_out, int out_size, void* d_ws, size_t ws_size,
                              hipStream_t stream) {
    const float* x      = (const float*)d_in[0];
    const int*   src    = (const int*)d_in[1];
    const int*   dst    = (const int*)d_in[2];
    const float* self_w = (const float*)d_in[3];
    const float* ppi_w  = (const float*)d_in[4];
    const float* W_in   = (const float*)d_in[5];
    const float* b_in   = (const float*)d_in[6];
    const float* W1     = (const float*)d_in[7];
    const float* b1     = (const float*)d_in[8];
    const float* W2     = (const float*)d_in[9];
    const float* b2     = (const float*)d_in[10];
    const float* W_out  = (const float*)d_in[11];
    const float* b_out  = (const float*)d_in[12];
    float* out = (float*)d_out;

    char* ws = (char*)d_ws;
    size_t o = 0;
    float* h   = (float*)(ws + o); o += (size_t)N_NODES * DH * 4;   // 25.6 MB
    float* agg = (float*)(ws + o); o += (size_t)N_NODES * DH * 4;   // 25.6 MB
    float* res = (float*)(ws + o); o += (size_t)N_NODES * DH * 4;   // 25.6 MB
    int* off = (int*)(ws + o); o += (((size_t)(N_NODES + 1) * 4 + 255) / 256) * 256;
    int* cur = (int*)(ws + o); o += (((size_t)N_NODES * 4 + 255) / 256) * 256;
    int* eid = (int*)(ws + o); o += (size_t)N_EDGES * 4;

    const int EB = (N_EDGES + 255) / 256;  // 3125

    // CSR build
    hipMemsetAsync(off, 0, (size_t)(N_NODES + 1) * 4, stream);
    count_deg_kernel<<<EB, 256, 0, stream>>>(dst, off);
    scan_kernel<<<1, 1024, 0, stream>>>(off);
    hipMemsetAsync(cur, 0, (size_t)N_NODES * 4, stream);
    scatter_eid_kernel<<<EB, 256, 0, stream>>>(dst, off, cur, eid);

    // input linear
    gemm_in_kernel<<<N_NODES / 8, 128, 0, stream>>>(x, W_in, b_in, h);

    // layer 1
    aggregate_kernel<<<N_NODES, 128, 0, stream>>>(h, off, eid, src, self_w, ppi_w, agg, res);
    gemm_update_kernel<<<N_NODES / 8, 128, 0, stream>>>(agg, res, W1, b1, h);

    // layer 2
    aggregate_kernel<<<N_NODES, 128, 0, stream>>>(h, off, eid, src, self_w, ppi_w, agg, res);
    gemm_update_kernel<<<N_NODES / 8, 128, 0, stream>>>(agg, res, W2, b2, h);

    // output linear
    gemm_out_kernel<<<dim3(4, N_NODES / 8), 256, 0, stream>>>(h, W_out, b_out, out);
}

// Round 2
// 790.644 us; speedup vs baseline: 1.5417x; 1.5417x over previous
//
#include <hip/hip_runtime.h>

#define N_NODES 50000
#define M_PAD   50048          // nodes padded to multiple of 64
#define N_EDGES 800000
#define DIN 256
#define DH  128
#define NL  1000
#define NL_PAD 1024

typedef unsigned short ushort_t;
typedef __attribute__((ext_vector_type(8))) short bf16x8;
typedef __attribute__((ext_vector_type(4))) float f32x4;

__device__ __forceinline__ ushort_t f32_to_bf16_rne(float f) {
    unsigned int u = __float_as_uint(f);
    unsigned int r = (u + 0x7FFFu + ((u >> 16) & 1u)) >> 16;
    return (ushort_t)r;
}

// ---------------- CSR build ----------------

__global__ void count_deg_kernel(const int* __restrict__ dst, int* __restrict__ deg) {
    int e = blockIdx.x * blockDim.x + threadIdx.x;
    if (e < N_EDGES) atomicAdd(&deg[dst[e]], 1);
}

// In-place exclusive scan of deg[0..N-1] -> offsets, writes off[N]=E. One block.
__global__ __launch_bounds__(1024) void scan_kernel(int* __restrict__ off) {
    __shared__ int lds[1024];
    const int t = threadIdx.x;
    const int CH = (N_NODES + 1023) / 1024;  // 49
    const int lo = t * CH;
    const int hi = (lo + CH < N_NODES) ? (lo + CH) : N_NODES;
    int s = 0;
    for (int i = lo; i < hi; ++i) s += off[i];
    lds[t] = s;
    __syncthreads();
    for (int o = 1; o < 1024; o <<= 1) {
        int v = (t >= o) ? lds[t - o] : 0;
        __syncthreads();
        lds[t] += v;
        __syncthreads();
    }
    int run = (t == 0) ? 0 : lds[t - 1];
    for (int i = lo; i < hi; ++i) {
        int v = off[i];
        off[i] = run;
        run += v;
    }
    if (t == 1023) off[N_NODES] = lds[1023];
}

// Scatter edges into dst-sorted fused arrays (kills the eid indirection).
__global__ void scatter_kernel(const int* __restrict__ dst, const int* __restrict__ src,
                               const float* __restrict__ self_w, const float* __restrict__ ppi_w,
                               const int* __restrict__ off, int* __restrict__ cur,
                               int* __restrict__ src_s, float* __restrict__ self_s,
                               float* __restrict__ ppi_s) {
    int e = blockIdx.x * blockDim.x + threadIdx.x;
    if (e < N_EDGES) {
        int d = dst[e];
        int p = off[d] + atomicAdd(&cur[d], 1);
        src_s[p]  = src[e];
        self_s[p] = self_w[e];
        ppi_s[p]  = ppi_w[e];
    }
}

// ---------------- B-operand pack (fragment-contiguous) ----------------
// pack[((nt*CH + c)*64 + lane)*8 + j] = bf16(W[k][n]), k=c*32+(lane>>4)*8+j,
// n = nt*16+(lane&15); zero-pad cols >= Nreal.
__global__ void pack_b_kernel(const float* __restrict__ W, ushort_t* __restrict__ Bp,
                              int K, int Nreal, int Npad) {
    const int CH = K / 32;
    int tid = blockIdx.x * blockDim.x + threadIdx.x;
    int total = (Npad / 16) * CH * 64;
    if (tid >= total) return;
    int lane = tid & 63;
    int c = (tid >> 6) % CH;
    int nt = (tid >> 6) / CH;
    int n = nt * 16 + (lane & 15);
    int kb = c * 32 + (lane >> 4) * 8;
    ushort_t v[8];
#pragma unroll
    for (int j = 0; j < 8; ++j)
        v[j] = (n < Nreal) ? f32_to_bf16_rne(W[(size_t)(kb + j) * Nreal + n]) : (ushort_t)0;
    ushort_t* p = Bp + (size_t)tid * 8;
#pragma unroll
    for (int j = 0; j < 8; ++j) p[j] = v[j];
}

// ---------------- MFMA GEMM template ----------------
// C[M x Nreal] = A[M x K] @ B  (+bias, opt relu, opt +res, opt bf16 copy)
// grid: (Npad/64, M_PAD/64), block 256 = 4 waves; wave: 64 rows x 16 cols.
template<int K, bool A_F32, bool RELU, bool ADD_RES, bool WRITE_F32, bool WRITE_BF16>
__global__ __launch_bounds__(256) void mfma_gemm_kernel(
    const void* __restrict__ A_, const ushort_t* __restrict__ Bp,
    const float* __restrict__ bias, const float* __restrict__ res,
    float* __restrict__ Cf, ushort_t* __restrict__ Cb,
    int Nreal, int Mstore)
{
    constexpr int CH = K / 32;
    const int lane = threadIdx.x & 63;
    const int w    = threadIdx.x >> 6;
    const int n0   = blockIdx.x * 64 + w * 16;
    const int nt   = blockIdx.x * 4 + w;
    const int r0   = blockIdx.y * 64;
    const int lr   = lane & 15;
    const int lq   = lane >> 4;

    const ushort_t* Ab = (const ushort_t*)A_;
    const float*    Af = (const float*)A_;

    int arow[4];
#pragma unroll
    for (int t = 0; t < 4; ++t) {
        int r = r0 + t * 16 + lr;
        if (A_F32) r = (r < N_NODES) ? r : (N_NODES - 1);  // clamp: pad rows unread downstream
        arow[t] = r;
    }

    f32x4 acc[4] = {f32x4{0,0,0,0}, f32x4{0,0,0,0}, f32x4{0,0,0,0}, f32x4{0,0,0,0}};

    for (int c = 0; c < CH; ++c) {
        bf16x8 bfrag = *(const bf16x8*)(Bp + ((size_t)(nt * CH + c) * 64 + lane) * 8);
        const int kb = c * 32 + lq * 8;
        bf16x8 afrag[4];
#pragma unroll
        for (int t = 0; t < 4; ++t) {
            if (A_F32) {
                float4 f0 = *(const float4*)(Af + (size_t)arow[t] * K + kb);
                float4 f1 = *(const float4*)(Af + (size_t)arow[t] * K + kb + 4);
                bf16x8 a;
                a[0] = (short)f32_to_bf16_rne(f0.x);
                a[1] = (short)f32_to_bf16_rne(f0.y);
                a[2] = (short)f32_to_bf16_rne(f0.z);
                a[3] = (short)f32_to_bf16_rne(f0.w);
                a[4] = (short)f32_to_bf16_rne(f1.x);
                a[5] = (short)f32_to_bf16_rne(f1.y);
                a[6] = (short)f32_to_bf16_rne(f1.z);
                a[7] = (short)f32_to_bf16_rne(f1.w);
                afrag[t] = a;
            } else {
                afrag[t] = *(const bf16x8*)(Ab + (size_t)arow[t] * K + kb);
            }
        }
#pragma unroll
        for (int t = 0; t < 4; ++t)
            acc[t] = __builtin_amdgcn_mfma_f32_16x16x32_bf16(afrag[t], bfrag, acc[t], 0, 0, 0);
    }

    const int col = n0 + lr;
    const float bv = (col < Nreal) ? bias[col] : 0.f;
#pragma unroll
    for (int t = 0; t < 4; ++t) {
#pragma unroll
        for (int i = 0; i < 4; ++i) {
            int row = r0 + t * 16 + lq * 4 + i;
            if (row < Mstore && col < Nreal) {
                float v = acc[t][i] + bv;
                if (RELU) v = fmaxf(v, 0.f);
                if (ADD_RES) v += res[(size_t)row * DH + col];
                if (WRITE_F32) Cf[(size_t)row * Nreal + col] = v;
                if (WRITE_BF16) Cb[(size_t)row * DH + col] = f32_to_bf16_rne(v);
            }
        }
    }
}

// ---------------- aggregation (pull, CSR, no indirection) ----------------
// agg_b[n] = bf16( sum ppi*h[src] ), res[n] = sum self*h[src]; pad nodes -> 0.
__global__ __launch_bounds__(128) void aggregate_kernel(
    const float* __restrict__ h, const int* __restrict__ off,
    const int* __restrict__ src_s, const float* __restrict__ self_s,
    const float* __restrict__ ppi_s,
    ushort_t* __restrict__ agg_b, float* __restrict__ res)
{
    const int node = blockIdx.x;
    const int d = threadIdx.x;
    float aa = 0.f, rr = 0.f;
    if (node < N_NODES) {
        const int lo = off[node], hi = off[node + 1];
        int i = lo;
        for (; i + 1 < hi; i += 2) {
            int s0 = src_s[i], s1 = src_s[i + 1];
            float wp0 = ppi_s[i], wp1 = ppi_s[i + 1];
            float ws0 = self_s[i], ws1 = self_s[i + 1];
            float v0 = h[(size_t)s0 * DH + d];
            float v1 = h[(size_t)s1 * DH + d];
            aa += wp0 * v0 + wp1 * v1;
            rr += ws0 * v0 + ws1 * v1;
        }
        if (i < hi) {
            int s0 = src_s[i];
            float v0 = h[(size_t)s0 * DH + d];
            aa += ppi_s[i] * v0;
            rr += self_s[i] * v0;
        }
    }
    agg_b[(size_t)node * DH + d] = f32_to_bf16_rne(aa);
    res[(size_t)node * DH + d] = rr;
}

// ---------------- launch ----------------

extern "C" void kernel_launch(void* const* d_in, const int* in_sizes, int n_in,
                              void* d_out, int out_size, void* d_ws, size_t ws_size,
                              hipStream_t stream) {
    const float* x      = (const float*)d_in[0];
    const int*   src    = (const int*)d_in[1];
    const int*   dst    = (const int*)d_in[2];
    const float* self_w = (const float*)d_in[3];
    const float* ppi_w  = (const float*)d_in[4];
    const float* W_in   = (const float*)d_in[5];
    const float* b_in   = (const float*)d_in[6];
    const float* W1     = (const float*)d_in[7];
    const float* b1     = (const float*)d_in[8];
    const float* W2     = (const float*)d_in[9];
    const float* b2     = (const float*)d_in[10];
    const float* W_out  = (const float*)d_in[11];
    const float* b_out  = (const float*)d_in[12];
    float* out = (float*)d_out;

    char* ws = (char*)d_ws;
    size_t o = 0;
    auto alloc = [&](size_t bytes) { void* p = ws + o; o += (bytes + 255) & ~(size_t)255; return p; };

    float*    h      = (float*)alloc((size_t)M_PAD * DH * 4);      // 25.6 MB
    float*    res    = (float*)alloc((size_t)M_PAD * DH * 4);      // 25.6 MB
    ushort_t* agg_b  = (ushort_t*)alloc((size_t)M_PAD * DH * 2);   // 12.8 MB
    ushort_t* hb     = (ushort_t*)alloc((size_t)M_PAD * DH * 2);   // 12.8 MB
    int*      off    = (int*)alloc((size_t)(N_NODES + 1) * 4);
    int*      cur    = (int*)alloc((size_t)N_NODES * 4);
    int*      src_s  = (int*)alloc((size_t)N_EDGES * 4);
    float*    self_s = (float*)alloc((size_t)N_EDGES * 4);
    float*    ppi_s  = (float*)alloc((size_t)N_EDGES * 4);
    ushort_t* Bp_in  = (ushort_t*)alloc((size_t)DIN * DH * 2);     // 64 KB
    ushort_t* Bp_1   = (ushort_t*)alloc((size_t)DH * DH * 2);      // 32 KB
    ushort_t* Bp_2   = (ushort_t*)alloc((size_t)DH * DH * 2);
    ushort_t* Bp_out = (ushort_t*)alloc((size_t)DH * NL_PAD * 2);  // 256 KB

    const int EB = (N_EDGES + 255) / 256;

    // CSR build
    hipMemsetAsync(off, 0, (size_t)(N_NODES + 1) * 4, stream);
    count_deg_kernel<<<EB, 256, 0, stream>>>(dst, off);
    scan_kernel<<<1, 1024, 0, stream>>>(off);
    hipMemsetAsync(cur, 0, (size_t)N_NODES * 4, stream);
    scatter_kernel<<<EB, 256, 0, stream>>>(dst, src, self_w, ppi_w, off, cur, src_s, self_s, ppi_s);

    // weight packs
    pack_b_kernel<<<(8 * 8 * 64 + 255) / 256, 256, 0, stream>>>(W_in, Bp_in, DIN, DH, DH);
    pack_b_kernel<<<(8 * 4 * 64 + 255) / 256, 256, 0, stream>>>(W1, Bp_1, DH, DH, DH);
    pack_b_kernel<<<(8 * 4 * 64 + 255) / 256, 256, 0, stream>>>(W2, Bp_2, DH, DH, DH);
    pack_b_kernel<<<(64 * 4 * 64 + 255) / 256, 256, 0, stream>>>(W_out, Bp_out, DH, NL, NL_PAD);

    const dim3 g_h(DH / 64, M_PAD / 64);       // (2, 782)
    const dim3 g_o(NL_PAD / 64, M_PAD / 64);   // (16, 782)

    // input linear: h = relu(x @ W_in + b_in)
    mfma_gemm_kernel<DIN, true, true, false, true, false>
        <<<g_h, 256, 0, stream>>>(x, Bp_in, b_in, nullptr, h, nullptr, DH, M_PAD);

    // layer 1
    aggregate_kernel<<<M_PAD, 128, 0, stream>>>(h, off, src_s, self_s, ppi_s, agg_b, res);
    mfma_gemm_kernel<DH, false, true, true, true, false>
        <<<g_h, 256, 0, stream>>>(agg_b, Bp_1, b1, res, h, nullptr, DH, M_PAD);

    // layer 2 (writes bf16 h for the output GEMM; skips f32 h)
    aggregate_kernel<<<M_PAD, 128, 0, stream>>>(h, off, src_s, self_s, ppi_s, agg_b, res);
    mfma_gemm_kernel<DH, false, true, true, false, true>
        <<<g_h, 256, 0, stream>>>(agg_b, Bp_2, b2, res, nullptr, hb, DH, M_PAD);

    // output linear: out = h @ W_out + b_out
    mfma_gemm_kernel<DH, false, false, false, true, false>
        <<<g_o, 256, 0, stream>>>(hb, Bp_out, b_out, nullptr, out, nullptr, NL, N_NODES);
}

// Round 3
// 723.031 us; speedup vs baseline: 1.6858x; 1.0935x over previous
//
#include <hip/hip_runtime.h>

#define N_NODES 50000
#define M_PAD   50048          // nodes padded to multiple of 64
#define N_EDGES 800000
#define DIN 256
#define DH  128
#define NL  1000
#define NL_PAD 1024

typedef unsigned short ushort_t;
typedef __attribute__((ext_vector_type(8))) short bf16x8;
typedef __attribute__((ext_vector_type(4))) float f32x4;

__device__ __forceinline__ ushort_t f32_to_bf16_rne(float f) {
    unsigned int u = __float_as_uint(f);
    unsigned int r = (u + 0x7FFFu + ((u >> 16) & 1u)) >> 16;
    return (ushort_t)r;
}
__device__ __forceinline__ float bf16_lo(unsigned u) { return __uint_as_float(u << 16); }
__device__ __forceinline__ float bf16_hi(unsigned u) { return __uint_as_float(u & 0xFFFF0000u); }

// ---------------- CSR build ----------------

__global__ void count_deg_kernel(const int* __restrict__ dst, int* __restrict__ deg) {
    int e = blockIdx.x * blockDim.x + threadIdx.x;
    if (e < N_EDGES) atomicAdd(&deg[dst[e]], 1);
}

// In-place exclusive scan of deg[0..N-1] -> offsets, writes off[N]=E. One block.
__global__ __launch_bounds__(1024) void scan_kernel(int* __restrict__ off) {
    __shared__ int lds[1024];
    const int t = threadIdx.x;
    const int CHN = (N_NODES + 1023) / 1024;  // 49
    const int lo = t * CHN;
    const int hi = (lo + CHN < N_NODES) ? (lo + CHN) : N_NODES;
    int s = 0;
    for (int i = lo; i < hi; ++i) s += off[i];
    lds[t] = s;
    __syncthreads();
    for (int o = 1; o < 1024; o <<= 1) {
        int v = (t >= o) ? lds[t - o] : 0;
        __syncthreads();
        lds[t] += v;
        __syncthreads();
    }
    int run = (t == 0) ? 0 : lds[t - 1];
    for (int i = lo; i < hi; ++i) {
        int v = off[i];
        off[i] = run;
        run += v;
    }
    if (t == 1023) off[N_NODES] = lds[1023];
}

// Scatter edges into dst-sorted fused arrays.
__global__ void scatter_kernel(const int* __restrict__ dst, const int* __restrict__ src,
                               const float* __restrict__ self_w, const float* __restrict__ ppi_w,
                               const int* __restrict__ off, int* __restrict__ cur,
                               int* __restrict__ src_s, float* __restrict__ self_s,
                               float* __restrict__ ppi_s) {
    int e = blockIdx.x * blockDim.x + threadIdx.x;
    if (e < N_EDGES) {
        int d = dst[e];
        int p = off[d] + atomicAdd(&cur[d], 1);
        src_s[p]  = src[e];
        self_s[p] = self_w[e];
        ppi_s[p]  = ppi_w[e];
    }
}

// ---------------- x -> bf16 (pad rows zeroed) ----------------
__global__ void cvt_x_kernel(const float* __restrict__ x, ushort_t* __restrict__ xb) {
    int tid = blockIdx.x * blockDim.x + threadIdx.x;
    const int total = M_PAD * (DIN / 8);
    if (tid >= total) return;
    int row = tid >> 5;             // DIN/8 = 32 chunks per row
    int c8 = (tid & 31) * 8;
    ushort_t v[8];
    if (row < N_NODES) {
        const float* p = x + (size_t)row * DIN + c8;
        float4 f0 = ((const float4*)p)[0];
        float4 f1 = ((const float4*)p)[1];
        v[0] = f32_to_bf16_rne(f0.x); v[1] = f32_to_bf16_rne(f0.y);
        v[2] = f32_to_bf16_rne(f0.z); v[3] = f32_to_bf16_rne(f0.w);
        v[4] = f32_to_bf16_rne(f1.x); v[5] = f32_to_bf16_rne(f1.y);
        v[6] = f32_to_bf16_rne(f1.z); v[7] = f32_to_bf16_rne(f1.w);
    } else {
#pragma unroll
        for (int j = 0; j < 8; ++j) v[j] = 0;
    }
    ushort_t* q = xb + (size_t)tid * 8;
#pragma unroll
    for (int j = 0; j < 8; ++j) q[j] = v[j];
}

// ---------------- fused B-operand pack (fragment-contiguous) ----------------
__device__ __forceinline__ void pack_one(const float* __restrict__ W, ushort_t* __restrict__ Bp,
                                         int K, int Nreal, int t) {
    const int CHN = K / 32;
    int lane = t & 63;
    int c = (t >> 6) % CHN;
    int nt = (t >> 6) / CHN;
    int n = nt * 16 + (lane & 15);
    int kb = c * 32 + (lane >> 4) * 8;
    ushort_t* p = Bp + (size_t)t * 8;
#pragma unroll
    for (int j = 0; j < 8; ++j)
        p[j] = (n < Nreal) ? f32_to_bf16_rne(W[(size_t)(kb + j) * Nreal + n]) : (ushort_t)0;
}

#define T_IN  ((DH / 16) * (DIN / 32) * 64)        // 4096
#define T_L   ((DH / 16) * (DH / 32) * 64)         // 2048
#define T_OUT ((NL_PAD / 16) * (DH / 32) * 64)     // 16384
#define T_ALL (T_IN + 2 * T_L + T_OUT)             // 24576

__global__ void pack_all_kernel(const float* __restrict__ W_in, const float* __restrict__ W1,
                                const float* __restrict__ W2, const float* __restrict__ W_out,
                                ushort_t* __restrict__ Bp_in, ushort_t* __restrict__ Bp_1,
                                ushort_t* __restrict__ Bp_2, ushort_t* __restrict__ Bp_out) {
    int tid = blockIdx.x * blockDim.x + threadIdx.x;
    if (tid < T_IN) pack_one(W_in, Bp_in, DIN, DH, tid);
    else if (tid < T_IN + T_L) pack_one(W1, Bp_1, DH, DH, tid - T_IN);
    else if (tid < T_IN + 2 * T_L) pack_one(W2, Bp_2, DH, DH, tid - T_IN - T_L);
    else if (tid < T_ALL) pack_one(W_out, Bp_out, DH, NL, tid - T_IN - 2 * T_L);
}

// ---------------- MFMA GEMM template ----------------
// grid: (Npad/(64*G), M_PAD/64), block 256 = 4 waves.
// Each block: 64 rows x 64*G cols; A-tile stays L1-resident across the G groups.
template<int K, int G, bool RELU, bool ADD_RES, bool WRITE_F32>
__global__ __launch_bounds__(256) void mfma_gemm_kernel(
    const ushort_t* __restrict__ A, const ushort_t* __restrict__ Bp,
    const float* __restrict__ bias, const ushort_t* __restrict__ res_b,
    float* __restrict__ Cf, ushort_t* __restrict__ Cb,
    int Nreal, int Mstore)
{
    constexpr int CHN = K / 32;
    const int lane = threadIdx.x & 63;
    const int w    = threadIdx.x >> 6;
    const int r0   = blockIdx.y * 64;
    const int lr   = lane & 15;
    const int lq   = lane >> 4;

    const ushort_t* arow[4];
#pragma unroll
    for (int t = 0; t < 4; ++t)
        arow[t] = A + (size_t)(r0 + t * 16 + lr) * K + lq * 8;

    for (int g = 0; g < G; ++g) {
        const int nt = (blockIdx.x * G + g) * 4 + w;
        f32x4 acc[4] = {f32x4{0,0,0,0}, f32x4{0,0,0,0}, f32x4{0,0,0,0}, f32x4{0,0,0,0}};
#pragma unroll
        for (int c = 0; c < CHN; ++c) {
            bf16x8 bfrag = *(const bf16x8*)(Bp + ((size_t)(nt * CHN + c) * 64 + lane) * 8);
#pragma unroll
            for (int t = 0; t < 4; ++t) {
                bf16x8 afrag = *(const bf16x8*)(arow[t] + c * 32);
                acc[t] = __builtin_amdgcn_mfma_f32_16x16x32_bf16(afrag, bfrag, acc[t], 0, 0, 0);
            }
        }
        const int col = nt * 16 + lr;
        const float bv = (col < Nreal) ? bias[col] : 0.f;
#pragma unroll
        for (int t = 0; t < 4; ++t) {
#pragma unroll
            for (int i = 0; i < 4; ++i) {
                int row = r0 + t * 16 + lq * 4 + i;
                if (row < Mstore && col < Nreal) {
                    float v = acc[t][i] + bv;
                    if (RELU) v = fmaxf(v, 0.f);
                    if (ADD_RES) v += bf16_lo((unsigned)res_b[(size_t)row * DH + col]);
                    if (WRITE_F32) Cf[(size_t)row * Nreal + col] = v;
                    else           Cb[(size_t)row * DH + col] = f32_to_bf16_rne(v);
                }
            }
        }
    }
}

// ---------------- aggregation: 1 wave/node, 2 dims/lane, bf16 h ----------------
__global__ __launch_bounds__(256) void aggregate_kernel(
    const ushort_t* __restrict__ hb, const int* __restrict__ off,
    const int* __restrict__ src_s, const float* __restrict__ self_s,
    const float* __restrict__ ppi_s,
    ushort_t* __restrict__ agg_b, ushort_t* __restrict__ res_b)
{
    const int node = blockIdx.x * 4 + (threadIdx.x >> 6);
    const int t = threadIdx.x & 63;
    float aa0 = 0.f, aa1 = 0.f, rr0 = 0.f, rr1 = 0.f;
    if (node < N_NODES) {
        const int lo = off[node], hi = off[node + 1];
        int i = lo;
        for (; i + 1 < hi; i += 2) {
            int s0 = src_s[i], s1 = src_s[i + 1];
            float wp0 = ppi_s[i], wp1 = ppi_s[i + 1];
            float ws0 = self_s[i], ws1 = self_s[i + 1];
            unsigned u0 = *(const unsigned*)(hb + (size_t)s0 * DH + 2 * t);
            unsigned u1 = *(const unsigned*)(hb + (size_t)s1 * DH + 2 * t);
            float a0 = bf16_lo(u0), b0 = bf16_hi(u0);
            float a1 = bf16_lo(u1), b1 = bf16_hi(u1);
            aa0 += wp0 * a0 + wp1 * a1;
            aa1 += wp0 * b0 + wp1 * b1;
            rr0 += ws0 * a0 + ws1 * a1;
            rr1 += ws0 * b0 + ws1 * b1;
        }
        if (i < hi) {
            int s0 = src_s[i];
            float wp0 = ppi_s[i], ws0 = self_s[i];
            unsigned u0 = *(const unsigned*)(hb + (size_t)s0 * DH + 2 * t);
            float a0 = bf16_lo(u0), b0 = bf16_hi(u0);
            aa0 += wp0 * a0; aa1 += wp0 * b0;
            rr0 += ws0 * a0; rr1 += ws0 * b0;
        }
    }
    unsigned pa = ((unsigned)f32_to_bf16_rne(aa1) << 16) | (unsigned)f32_to_bf16_rne(aa0);
    unsigned pr = ((unsigned)f32_to_bf16_rne(rr1) << 16) | (unsigned)f32_to_bf16_rne(rr0);
    *(unsigned*)(agg_b + (size_t)node * DH + 2 * t) = pa;
    *(unsigned*)(res_b + (size_t)node * DH + 2 * t) = pr;
}

// ---------------- launch ----------------

extern "C" void kernel_launch(void* const* d_in, const int* in_sizes, int n_in,
                              void* d_out, int out_size, void* d_ws, size_t ws_size,
                              hipStream_t stream) {
    const float* x      = (const float*)d_in[0];
    const int*   src    = (const int*)d_in[1];
    const int*   dst    = (const int*)d_in[2];
    const float* self_w = (const float*)d_in[3];
    const float* ppi_w  = (const float*)d_in[4];
    const float* W_in   = (const float*)d_in[5];
    const float* b_in   = (const float*)d_in[6];
    const float* W1     = (const float*)d_in[7];
    const float* b1     = (const float*)d_in[8];
    const float* W2     = (const float*)d_in[9];
    const float* b2     = (const float*)d_in[10];
    const float* W_out  = (const float*)d_in[11];
    const float* b_out  = (const float*)d_in[12];
    float* out = (float*)d_out;

    char* ws = (char*)d_ws;
    size_t o = 0;
    auto alloc = [&](size_t bytes) { void* p = ws + o; o += (bytes + 255) & ~(size_t)255; return p; };

    ushort_t* xb     = (ushort_t*)alloc((size_t)M_PAD * DIN * 2);  // 25.6 MB
    ushort_t* hb     = (ushort_t*)alloc((size_t)M_PAD * DH * 2);   // 12.8 MB
    ushort_t* agg_b  = (ushort_t*)alloc((size_t)M_PAD * DH * 2);   // 12.8 MB
    ushort_t* res_b  = (ushort_t*)alloc((size_t)M_PAD * DH * 2);   // 12.8 MB
    int*      off    = (int*)alloc((size_t)(2 * N_NODES + 1) * 4); // off + cur contiguous
    int*      cur    = off + N_NODES + 1;
    int*      src_s  = (int*)alloc((size_t)N_EDGES * 4);
    float*    self_s = (float*)alloc((size_t)N_EDGES * 4);
    float*    ppi_s  = (float*)alloc((size_t)N_EDGES * 4);
    ushort_t* Bp_in  = (ushort_t*)alloc((size_t)T_IN * 8 * 2);
    ushort_t* Bp_1   = (ushort_t*)alloc((size_t)T_L * 8 * 2);
    ushort_t* Bp_2   = (ushort_t*)alloc((size_t)T_L * 8 * 2);
    ushort_t* Bp_out = (ushort_t*)alloc((size_t)T_OUT * 8 * 2);

    const int EB = (N_EDGES + 255) / 256;

    // CSR build
    hipMemsetAsync(off, 0, (size_t)(2 * N_NODES + 1) * 4, stream);
    count_deg_kernel<<<EB, 256, 0, stream>>>(dst, off);
    scan_kernel<<<1, 1024, 0, stream>>>(off);
    scatter_kernel<<<EB, 256, 0, stream>>>(dst, src, self_w, ppi_w, off, cur, src_s, self_s, ppi_s);

    // weight packs + x conversion
    pack_all_kernel<<<(T_ALL + 255) / 256, 256, 0, stream>>>(W_in, W1, W2, W_out,
                                                             Bp_in, Bp_1, Bp_2, Bp_out);
    cvt_x_kernel<<<(M_PAD * (DIN / 8) + 255) / 256, 256, 0, stream>>>(x, xb);

    const dim3 g_h(1, M_PAD / 64);   // DH GEMMs: G=2 -> grid.x = 128/128 = 1
    const dim3 g_o(4, M_PAD / 64);   // out GEMM: G=4 -> grid.x = 1024/256 = 4

    // input linear: hb = relu(xb @ W_in + b_in)
    mfma_gemm_kernel<DIN, 2, true, false, false>
        <<<g_h, 256, 0, stream>>>(xb, Bp_in, b_in, nullptr, nullptr, hb, DH, M_PAD);

    // layer 1
    aggregate_kernel<<<M_PAD / 4, 256, 0, stream>>>(hb, off, src_s, self_s, ppi_s, agg_b, res_b);
    mfma_gemm_kernel<DH, 2, true, true, false>
        <<<g_h, 256, 0, stream>>>(agg_b, Bp_1, b1, res_b, nullptr, hb, DH, M_PAD);

    // layer 2
    aggregate_kernel<<<M_PAD / 4, 256, 0, stream>>>(hb, off, src_s, self_s, ppi_s, agg_b, res_b);
    mfma_gemm_kernel<DH, 2, true, true, false>
        <<<g_h, 256, 0, stream>>>(agg_b, Bp_2, b2, res_b, nullptr, hb, DH, M_PAD);

    // output linear: out = hb @ W_out + b_out
    mfma_gemm_kernel<DH, 4, false, false, true>
        <<<g_o, 256, 0, stream>>>(hb, Bp_out, b_out, nullptr, out, nullptr, NL, N_NODES);
}